// Round 4
// baseline (1116.809 us; speedup 1.0000x reference)
//
#include <hip/hip_runtime.h>
#include <math.h>
#include <float.h>

#define N_NODES 1024
#define IN_CH   1433
#define HID     16
#define OUT_CH  7
#define N_EDGES 4096
#define E_TOT   5120   // N_EDGES + N_NODES (self loops)
#define N_TE    5119   // E_TOT - 1 (embedded series length)
#define N_TEP   5120   // pitch for per-rank arrays
#define NBUCK   1024
#define IB      20     // ceil(N_TE / 256)
#define BIGF    1e30f

__device__ __forceinline__ int src_of(const int* ei, int t) {
    return (t < N_EDGES) ? ei[t] : t - N_EDGES;
}
__device__ __forceinline__ int dst_of(const int* ei, int t) {
    return (t < N_EDGES) ? ei[N_EDGES + t] : t - N_EDGES;
}

// psi(x) for integer-valued x >= 0. Recurrence to x>=6 then asymptotic.
__device__ __forceinline__ float digammaf_dev(float x) {
    float r = 0.0f;
    while (x < 6.0f) { r -= 1.0f / x; x += 1.0f; }
    float inv  = 1.0f / x;
    float inv2 = inv * inv;
    r += logf(x) - 0.5f * inv
       - inv2 * (1.0f/12.0f - inv2 * (1.0f/120.0f - inv2 * (1.0f/252.0f)));
    return r;
}

__global__ __launch_bounds__(256) void gemm1_kernel(
    const float* __restrict__ x, const float* __restrict__ W1,
    const float* __restrict__ b1, float* __restrict__ h1) {
    __shared__ float xrow[IN_CH];
    const int r = blockIdx.x;
    const float* xr = x + (size_t)r * IN_CH;
    for (int k = threadIdx.x; k < IN_CH; k += 256) xrow[k] = xr[k];
    __syncthreads();
    const int o = threadIdx.x >> 4;
    const int g = threadIdx.x & 15;
    const float* wp = W1 + o * IN_CH;
    float s = 0.0f;
    for (int k = g; k < IN_CH; k += 16) s += xrow[k] * wp[k];
    #pragma unroll
    for (int m = 8; m >= 1; m >>= 1) s += __shfl_xor(s, m, 16);
    if (g == 0) h1[r * HID + o] = s + b1[o];
}

__global__ void cnt_kernel(const int* __restrict__ ei, float* __restrict__ cnt) {
    int e = blockIdx.x * blockDim.x + threadIdx.x;
    if (e >= E_TOT) return;
    atomicAdd(&cnt[dst_of(ei, e)], 1.0f);
}

// Bucket scatter: approx y-order (monotone across buckets, arbitrary within).
// One block (1024 thr) per channel. Outputs ys_tmp/idx_tmp (bucket-ordered),
// bstart[c][b] exclusive bucket offsets (bstart[NBUCK]=N_TE), meta = (lo, sc).
__global__ __launch_bounds__(1024) void sortA_kernel(
    const float* __restrict__ h, const int* __restrict__ ei, int C,
    float* __restrict__ ys_tmp, int* __restrict__ idx_tmp,
    int* __restrict__ bstart, float* __restrict__ meta) {
    const int c = blockIdx.x;
    const int tid = threadIdx.x;
    __shared__ unsigned int hist[NBUCK];
    __shared__ float wmn[16], wmx[16];
    __shared__ float s_lo, s_sc;
    float mn = BIGF, mx = -BIGF;
    for (int t = tid; t < N_TE; t += 1024) {
        float v = h[src_of(ei, t) * C + c];
        mn = fminf(mn, v); mx = fmaxf(mx, v);
    }
    #pragma unroll
    for (int m = 32; m >= 1; m >>= 1) {
        mn = fminf(mn, __shfl_xor(mn, m, 64));
        mx = fmaxf(mx, __shfl_xor(mx, m, 64));
    }
    if ((tid & 63) == 0) { wmn[tid >> 6] = mn; wmx[tid >> 6] = mx; }
    hist[tid] = 0u;
    __syncthreads();
    if (tid == 0) {
        float a = wmn[0], b = wmx[0];
        for (int k = 1; k < 16; ++k) { a = fminf(a, wmn[k]); b = fmaxf(b, wmx[k]); }
        s_lo = a;
        s_sc = (b > a) ? (float)(NBUCK - 1) / (b - a) : 0.0f;
        meta[2 * c] = a; meta[2 * c + 1] = s_sc;
    }
    __syncthreads();
    const float lo = s_lo, sc = s_sc;
    for (int t = tid; t < N_TE; t += 1024) {
        float v = h[src_of(ei, t) * C + c];
        int b = min(max((int)((v - lo) * sc), 0), NBUCK - 1);
        atomicAdd(&hist[b], 1u);
    }
    __syncthreads();
    for (int off = 1; off < NBUCK; off <<= 1) {   // inclusive scan
        unsigned v = hist[tid];
        unsigned add = (tid >= off) ? hist[tid - off] : 0u;
        __syncthreads();
        hist[tid] = v + add;
        __syncthreads();
    }
    unsigned excl = (tid > 0) ? hist[tid - 1] : 0u;
    __syncthreads();
    hist[tid] = excl;
    bstart[c * (NBUCK + 1) + tid] = (int)excl;
    if (tid == 0) bstart[c * (NBUCK + 1) + NBUCK] = N_TE;
    __syncthreads();
    for (int t = tid; t < N_TE; t += 1024) {
        float v = h[src_of(ei, t) * C + c];
        int b = min(max((int)((v - lo) * sc), 0), NBUCK - 1);
        unsigned r = atomicAdd(&hist[b], 1u);
        ys_tmp[c * N_TEP + r] = v;
        idx_tmp[c * N_TEP + r] = t;
    }
}

// Exact refine: rank each element within its small bucket by (y, orig idx),
// write final sorted y and gathered (x, z) payloads.
__global__ __launch_bounds__(256) void sortB_kernel(
    const float* __restrict__ h, const int* __restrict__ ei, int C,
    const float* __restrict__ ys_tmp, const int* __restrict__ idx_tmp,
    const int* __restrict__ bstart, const float* __restrict__ meta,
    float* __restrict__ ys_s, float* __restrict__ xzs_s) {
    const int c = blockIdx.y;
    const int r = blockIdx.x * 256 + threadIdx.x;
    if (r >= N_TE) return;
    const float y = ys_tmp[c * N_TEP + r];
    const int t = idx_tmp[c * N_TEP + r];
    const float lo = meta[2 * c], sc = meta[2 * c + 1];
    int b = min(max((int)((y - lo) * sc), 0), NBUCK - 1);
    const int s = bstart[c * (NBUCK + 1) + b];
    const int e = bstart[c * (NBUCK + 1) + b + 1];
    int cnt = 0;
    for (int q = s; q < e; ++q) {
        float yq = ys_tmp[c * N_TEP + q];
        int tq = idx_tmp[c * N_TEP + q];
        cnt += (yq < y || (yq == y && tq < t)) ? 1 : 0;
    }
    const int pos = s + cnt;
    ys_s[c * N_TEP + pos] = y;
    xzs_s[c * 2 * N_TEP + 2 * pos]     = h[dst_of(ei, t) * C + c];
    xzs_s[c * 2 * N_TEP + 2 * pos + 1] = h[src_of(ei, t + 1) * C + c];
}

// Fused KSG TE: eps walk + count walk over y-sorted arrays + digamma + reduce.
// grid = (IB, C). Walks stop when frontier |dy| >= e (sorted => safe).
__global__ __launch_bounds__(256) void te_kernel(
    const float* __restrict__ ys_s, const float* __restrict__ xzs_s,
    float* __restrict__ tes) {
    __shared__ float sy[N_TEP + 4];
    __shared__ float sxz[2 * N_TEP + 8];
    __shared__ float wsum[4];
    const int c = blockIdx.y;
    {
        const float* gy = ys_s + c * N_TEP;
        for (int t = threadIdx.x; t < N_TEP + 4; t += 256)
            sy[t] = (t < N_TE) ? gy[t] : BIGF;
        const float* gxz = xzs_s + c * 2 * N_TEP;
        for (int t = threadIdx.x; t < 2 * N_TEP + 8; t += 256)
            sxz[t] = (t < 2 * N_TE) ? gxz[t] : BIGF;
    }
    __syncthreads();

    const int p = blockIdx.x * 256 + threadIdx.x;   // sorted rank
    float local = 0.0f;
    if (p < N_TE) {
        const float yi = sy[p];
        const float xi = sxz[2 * p];
        const float zi = sxz[2 * p + 1];
        const int ga = (p + 4) & ~3;                       // aligned right start
        const int gtop = (p >= 1) ? (((p - 1) >> 2) << 2) : 0;

        // ---- eps: 1-NN in Chebyshev(x,y,z), diagonal excluded by construction
        float e = BIGF;
        for (int q = p + 1; q < ga; ++q) {                 // right prologue (pads safe)
            float dy = sy[q] - yi;
            float d = fmaxf(dy, fmaxf(fabsf(sxz[2*q] - xi), fabsf(sxz[2*q+1] - zi)));
            e = fminf(e, d);
        }
        if (p >= 1) {
            for (int q = p - 1; q >= gtop; --q) {          // left prologue
                float dy = yi - sy[q];
                float d = fmaxf(dy, fmaxf(fabsf(sxz[2*q] - xi), fabsf(sxz[2*q+1] - zi)));
                e = fminf(e, d);
            }
        }
        for (int g = ga;;) {                               // right main, aligned x4
            float4 y4 = *(const float4*)(sy + g);
            float4 a4 = *(const float4*)(sxz + 2 * g);
            float4 b4 = *(const float4*)(sxz + 2 * g + 4);
            float dy0 = y4.x - yi;
            if (dy0 >= e) break;
            float d0 = fmaxf(dy0,       fmaxf(fabsf(a4.x - xi), fabsf(a4.y - zi)));
            float d1 = fmaxf(y4.y - yi, fmaxf(fabsf(a4.z - xi), fabsf(a4.w - zi)));
            float d2 = fmaxf(y4.z - yi, fmaxf(fabsf(b4.x - xi), fabsf(b4.y - zi)));
            float d3 = fmaxf(y4.w - yi, fmaxf(fabsf(b4.z - xi), fabsf(b4.w - zi)));
            e = fminf(e, fminf(fminf(d0, d1), fminf(d2, d3)));
            g += 4;
        }
        for (int g = (p >= 1) ? gtop - 4 : -1; g >= 0;) {  // left main
            float4 y4 = *(const float4*)(sy + g);
            float4 a4 = *(const float4*)(sxz + 2 * g);
            float4 b4 = *(const float4*)(sxz + 2 * g + 4);
            float dy3 = yi - y4.w;
            if (dy3 >= e) break;
            float d0 = fmaxf(yi - y4.x, fmaxf(fabsf(a4.x - xi), fabsf(a4.y - zi)));
            float d1 = fmaxf(yi - y4.y, fmaxf(fabsf(a4.z - xi), fabsf(a4.w - zi)));
            float d2 = fmaxf(yi - y4.z, fmaxf(fabsf(b4.x - xi), fabsf(b4.y - zi)));
            float d3 = fmaxf(dy3,       fmaxf(fabsf(b4.z - xi), fabsf(b4.w - zi)));
            e = fminf(e, fminf(fminf(d0, d1), fminf(d2, d3)));
            g -= 4;
        }

        // ---- counts: window |dy| < eps; self-hit cancels the +1 in psi(n+1)
        const float eps = e;
        int ny = 0, nxy = 0, nyz = 0;
        if (eps > 0.0f) { ny = 1; nxy = 1; nyz = 1; }      // diagonal j==i
        for (int q = p + 1; q < ga; ++q) {
            float dy = sy[q] - yi;
            int by = dy < eps;
            ny  += by;
            nxy += by & (int)(fabsf(sxz[2*q] - xi) < eps);
            nyz += by & (int)(fabsf(sxz[2*q+1] - zi) < eps);
        }
        if (p >= 1) {
            for (int q = p - 1; q >= gtop; --q) {
                float dy = yi - sy[q];
                int by = dy < eps;
                ny  += by;
                nxy += by & (int)(fabsf(sxz[2*q] - xi) < eps);
                nyz += by & (int)(fabsf(sxz[2*q+1] - zi) < eps);
            }
        }
        for (int g = ga;;) {
            float4 y4 = *(const float4*)(sy + g);
            float4 a4 = *(const float4*)(sxz + 2 * g);
            float4 b4 = *(const float4*)(sxz + 2 * g + 4);
            float dy0 = y4.x - yi;
            if (dy0 >= eps) break;
            int by1 = (y4.y - yi) < eps;
            int by2 = (y4.z - yi) < eps;
            int by3 = (y4.w - yi) < eps;
            ny  += 1 + by1 + by2 + by3;
            nxy += (int)(fabsf(a4.x - xi) < eps) + (by1 & (int)(fabsf(a4.z - xi) < eps))
                 + (by2 & (int)(fabsf(b4.x - xi) < eps)) + (by3 & (int)(fabsf(b4.z - xi) < eps));
            nyz += (int)(fabsf(a4.y - zi) < eps) + (by1 & (int)(fabsf(a4.w - zi) < eps))
                 + (by2 & (int)(fabsf(b4.y - zi) < eps)) + (by3 & (int)(fabsf(b4.w - zi) < eps));
            g += 4;
        }
        for (int g = (p >= 1) ? gtop - 4 : -1; g >= 0;) {
            float4 y4 = *(const float4*)(sy + g);
            float4 a4 = *(const float4*)(sxz + 2 * g);
            float4 b4 = *(const float4*)(sxz + 2 * g + 4);
            float dy3 = yi - y4.w;
            if (dy3 >= eps) break;
            int by0 = (yi - y4.x) < eps;
            int by1 = (yi - y4.y) < eps;
            int by2 = (yi - y4.z) < eps;
            ny  += by0 + by1 + by2 + 1;
            nxy += (by0 & (int)(fabsf(a4.x - xi) < eps)) + (by1 & (int)(fabsf(a4.z - xi) < eps))
                 + (by2 & (int)(fabsf(b4.x - xi) < eps)) + (int)(fabsf(b4.z - xi) < eps);
            nyz += (by0 & (int)(fabsf(a4.y - zi) < eps)) + (by1 & (int)(fabsf(a4.w - zi) < eps))
                 + (by2 & (int)(fabsf(b4.y - zi) < eps)) + (int)(fabsf(b4.w - zi) < eps);
            g -= 4;
        }
        local = digammaf_dev((float)ny) - digammaf_dev((float)nxy)
              - digammaf_dev((float)nyz);
    }
    #pragma unroll
    for (int m = 32; m >= 1; m >>= 1) local += __shfl_xor(local, m, 64);
    if ((threadIdx.x & 63) == 0) wsum[threadIdx.x >> 6] = local;
    __syncthreads();
    if (threadIdx.x == 0)
        atomicAdd(&tes[c], wsum[0] + wsum[1] + wsum[2] + wsum[3]);
}

template <int C>
__global__ void agg_kernel(const float* __restrict__ h, const int* __restrict__ ei,
                           const float* __restrict__ tes_accum, float half_scale,
                           float* __restrict__ sums) {
    int idx = blockIdx.x * blockDim.x + threadIdx.x;
    if (idx >= E_TOT * C) return;
    int e = idx / C, c = idx % C;
    float te = (-0.57721566490153286f + tes_accum[c] * (1.0f / (float)N_TE)) * half_scale;
    float xj = h[src_of(ei, e) * C + c];
    float m = 1.0f / (1.0f + expf(-te * xj));
    atomicAdd(&sums[dst_of(ei, e) * C + c], m);
}

__global__ void fin1_kernel(const float* __restrict__ sums, const float* __restrict__ cnt,
                            float* __restrict__ h1a) {
    int idx = blockIdx.x * blockDim.x + threadIdx.x;
    if (idx >= N_NODES * HID) return;
    int v = idx / HID;
    float val = sums[idx] / fmaxf(cnt[v], 1.0f);
    h1a[idx] = fmaxf(val, 0.0f);
}

__global__ void gemm2_kernel(const float* __restrict__ h1a, const float* __restrict__ W2,
                             const float* __restrict__ b2, float* __restrict__ h2) {
    int idx = blockIdx.x * blockDim.x + threadIdx.x;
    if (idx >= N_NODES * OUT_CH) return;
    int v = idx / OUT_CH, o = idx % OUT_CH;
    float s = b2[o];
    #pragma unroll
    for (int k = 0; k < HID; ++k) s += h1a[v * HID + k] * W2[o * HID + k];
    h2[idx] = s;
}

__global__ void fin2_kernel(const float* __restrict__ sums2, const float* __restrict__ cnt,
                            float* __restrict__ out) {
    int v = blockIdx.x * blockDim.x + threadIdx.x;
    if (v >= N_NODES) return;
    float c = fmaxf(cnt[v], 1.0f);
    float vals[OUT_CH];
    float mx = -INFINITY;
    #pragma unroll
    for (int o = 0; o < OUT_CH; ++o) {
        vals[o] = sums2[v * OUT_CH + o] / c;
        mx = fmaxf(mx, vals[o]);
    }
    float se = 0.0f;
    #pragma unroll
    for (int o = 0; o < OUT_CH; ++o) se += expf(vals[o] - mx);
    float lse = mx + logf(se);
    #pragma unroll
    for (int o = 0; o < OUT_CH; ++o) out[v * OUT_CH + o] = vals[o] - lse;
}

extern "C" void kernel_launch(void* const* d_in, const int* in_sizes, int n_in,
                              void* d_out, int out_size, void* d_ws, size_t ws_size,
                              hipStream_t stream) {
    const float* x  = (const float*)d_in[0];
    const int*   ei = (const int*)  d_in[1];
    const float* W1 = (const float*)d_in[2];
    const float* b1 = (const float*)d_in[3];
    const float* W2 = (const float*)d_in[4];
    const float* b2 = (const float*)d_in[5];
    float* out = (float*)d_out;

    float* w = (float*)d_ws;
    size_t o = 0;
    // ---- zeroed region (atomic accumulators) ----
    float* sums1 = w + o; o += N_NODES * HID;
    float* sums2 = w + o; o += N_NODES * OUT_CH;
    float* cdeg  = w + o; o += N_NODES;
    float* tes1  = w + o; o += 16;
    float* tes2  = w + o; o += 16;
    const size_t zero_elems = o;
    // ---- non-zeroed region (sort buffers shared between layers) ----
    float* h1      = w + o; o += N_NODES * HID;
    float* h1a     = w + o; o += N_NODES * HID;
    float* h2      = w + o; o += N_NODES * OUT_CH;
    float* ys_tmp  = w + o; o += HID * N_TEP;
    int*   idx_tmp = (int*)(w + o); o += HID * N_TEP;
    float* ys_srt  = w + o; o += HID * N_TEP;
    float* xzs_srt = w + o; o += HID * 2 * N_TEP;
    int*   bstart  = (int*)(w + o); o += HID * (NBUCK + 1);
    float* meta    = w + o; o += 2 * HID;

    hipMemsetAsync(d_ws, 0, zero_elems * sizeof(float), stream);

    gemm1_kernel<<<N_NODES, 256, 0, stream>>>(x, W1, b1, h1);
    cnt_kernel<<<(E_TOT + 255) / 256, 256, 0, stream>>>(ei, cdeg);

    // ---- layer 1 ----
    sortA_kernel<<<HID, 1024, 0, stream>>>(h1, ei, HID, ys_tmp, idx_tmp, bstart, meta);
    sortB_kernel<<<dim3(IB, HID), 256, 0, stream>>>(h1, ei, HID, ys_tmp, idx_tmp,
                                                    bstart, meta, ys_srt, xzs_srt);
    te_kernel<<<dim3(IB, HID), 256, 0, stream>>>(ys_srt, xzs_srt, tes1);
    agg_kernel<HID><<<(E_TOT * HID + 255) / 256, 256, 0, stream>>>(h1, ei, tes1, 1.0f, sums1);
    fin1_kernel<<<(N_NODES * HID + 255) / 256, 256, 0, stream>>>(sums1, cdeg, h1a);

    // ---- layer 2 ----
    gemm2_kernel<<<(N_NODES * OUT_CH + 255) / 256, 256, 0, stream>>>(h1a, W2, b2, h2);
    sortA_kernel<<<OUT_CH, 1024, 0, stream>>>(h2, ei, OUT_CH, ys_tmp, idx_tmp, bstart, meta);
    sortB_kernel<<<dim3(IB, OUT_CH), 256, 0, stream>>>(h2, ei, OUT_CH, ys_tmp, idx_tmp,
                                                       bstart, meta, ys_srt, xzs_srt);
    te_kernel<<<dim3(IB, OUT_CH), 256, 0, stream>>>(ys_srt, xzs_srt, tes2);
    agg_kernel<OUT_CH><<<(E_TOT * OUT_CH + 255) / 256, 256, 0, stream>>>(h2, ei, tes2, 0.5f, sums2);
    fin2_kernel<<<(N_NODES + 255) / 256, 256, 0, stream>>>(sums2, cdeg, out);
}